// Round 6
// baseline (413.567 us; speedup 1.0000x reference)
//
#include <hip/hip_runtime.h>
#include <math.h>

// Problem constants
#define NRES     64
#define EXPRN    4
#define B_TOT    256           // NRES * EXPRN flattened rows
#define NC       1025          // N_COEFFS
#define NF       128           // N_FRAMES
#define HOP      1024
#define MHALF    1024          // half-size complex FFT length (WINDOW/2)
#define NTHREADS 512
#define CHUNK    32            // frames per block
#define NCHUNK   4             // chunks per row

// Padded LDS index for float2 z array: breaks pow2 strides; stage-read
// patterns verified conflict-free per 16-lane phase.
__device__ __forceinline__ int P2(int a) { return a + (a >> 4); }

__device__ __forceinline__ uint32_t rotl32(uint32_t x, int r) {
  return (x << r) | (x >> (32 - r));
}

// Bit-exact jax.random.uniform(key(42), minval=-1, maxval=1) under the modern
// default jax_threefry_partitionable=True path: bits = x0 ^ x1 of
// threefry2x32((0,42), (hi=0, lo=i)).
__device__ __forceinline__ float tf_noise(uint32_t i) {
  const uint32_t k0 = 0u, k1 = 42u;
  const uint32_t k2 = 0x1BD11BDAu ^ k0 ^ k1;
  uint32_t x0 = 0u + k0;
  uint32_t x1 = i + k1;
#define TF_ROUND(r) { x0 += x1; x1 = rotl32(x1, r); x1 ^= x0; }
  TF_ROUND(13) TF_ROUND(15) TF_ROUND(26) TF_ROUND(6)
  x0 += k1; x1 += k2 + 1u;
  TF_ROUND(17) TF_ROUND(29) TF_ROUND(16) TF_ROUND(24)
  x0 += k2; x1 += k0 + 2u;
  TF_ROUND(13) TF_ROUND(15) TF_ROUND(26) TF_ROUND(6)
  x0 += k0; x1 += k1 + 3u;
  TF_ROUND(17) TF_ROUND(29) TF_ROUND(16) TF_ROUND(24)
  x0 += k1; x1 += k2 + 4u;
  TF_ROUND(13) TF_ROUND(15) TF_ROUND(26) TF_ROUND(6)
  x0 += k2; x1 += k0 + 5u;
#undef TF_ROUND
  uint32_t bits = x0 ^ x1;
  float f = __uint_as_float((bits >> 9) | 0x3f800000u) - 1.0f;  // [0,1) exact
  return f * 2.0f - 1.0f;
}

// ---- Kernel 1: noise prefix sums at chunk boundaries ----
// P(b,c,j) = sum_{s < 32j-1} noise((b*NF+s)*NC + c), j = 1..3, into
// ws[(b*NC + c)*3 + (j-1)]. Pure function of indices (no inputs).
__global__ __launch_bounds__(256)
void prefix_kernel(float* __restrict__ ws) {
  const int flat = blockIdx.x * 256 + threadIdx.x;   // 0 .. 256*1025-1 exactly
  const int b = flat / NC;
  const int c = flat - b * NC;
  uint32_t idx = (uint32_t)(b * NF) * (uint32_t)NC + (uint32_t)c;
  float acc = 0.0f, p1 = 0.0f, p2 = 0.0f;
  for (int s = 0; s < 95; ++s) {
    if (s == 31) p1 = acc;
    if (s == 63) p2 = acc;
    acc += tf_noise(idx);
    idx += NC;
  }
  float* w = ws + (size_t)flat * 3;
  w[0] = p1; w[1] = p2; w[2] = acc;   // acc = sum s<95
}

// ---- Kernel 2: spectrum -> irfft -> overlap-add ----
__global__ __launch_bounds__(NTHREADS, 6)
void resblock_kernel(const float* __restrict__ amp,
                     const float* __restrict__ phase,
                     const float* __restrict__ decay,
                     const float* __restrict__ pdith,
                     const float* __restrict__ pre,
                     float* __restrict__ out) {
  __shared__ float2 z[MHALF + MHALF / 16];
  __shared__ float2 tw[MHALF];   // packed per-stage twiddles: tw[half+rr] = e^{+i*pi*rr/half}

  const int tid = threadIdx.x;
  const int k = tid;                 // owns spectrum pair (k, 1024-k)
  const int b = blockIdx.x;          // row = r*4 + e
  const int j = blockIdx.y;          // frame chunk
  const int t0 = j * CHUNK;
  const int tstart = (j == 0) ? 0 : (t0 - 1);   // one carry-only warmup frame
  const int tend = t0 + CHUNK;
  const int r = b >> 2, e = b & 3;
  const int base = r * (NC * EXPRN) + e;        // input layout (64,1025,4)
  const float PI_F = 3.14159265358979323846f;

  // ---- packed twiddle table (conflict-free stage reads) ----
  for (int i = tid; i < MHALF; i += NTHREADS) {
    float cs = 1.0f, sn = 0.0f;
    if (i > 0) {
      const int half = 1 << (31 - __clz(i));
      const int rr = i - half;
      float ang = PI_F * (float)rr / (float)half;
      sincosf(ang, &sn, &cs);
    }
    tw[i] = make_float2(cs, sn);
  }

  // ---- per-thread register chains: A = coeff k, B = coeff 1024-k, M = 512 (tid 0) ----
  float spA, dthA, coefA, magA, phiA; uint32_t idxA;
  float spB, dthB, coefB, magB, phiB; uint32_t idxB;
  float spM = 0, dthM = 0, coefM = 1, magM = 0, phiM = 0; uint32_t idxM = 0;

  auto load_chain = [&](int c, float& sp, float& dth, float& coef,
                        float& mag, float& phi, uint32_t& idx) {
    const int gi = base + c * EXPRN;
    const float a = amp[gi], p = phase[gi], d0 = decay[gi], pd = pdith[gi];
    const float sig = 1.0f / (1.0f + expf(-d0));
    const float coeff = 0.5f + 0.495f * sig;     // BASE_RES + sig*0.5*0.99
    coef = coeff;
    const float lgc = logf(coeff);
    const float smN = a * a * (1.0f / 1024.0f);  // fold 1/M irfft norm
    sp  = tanhf(p) * PI_F;
    dth = tanhf(pd);
    idx = (uint32_t)(b * NF + tstart) * (uint32_t)NC + (uint32_t)c;
    const float P = (j == 0) ? 0.0f : pre[((size_t)b * NC + c) * 3 + (j - 1)];
    phi = (float)tstart * sp + dth * P;
    mag = smN * expf((float)tstart * lgc);
  };
  load_chain(k,         spA, dthA, coefA, magA, phiA, idxA);
  load_chain(MHALF - k, spB, dthB, coefB, magB, phiB, idxB);
  if (k == 0) load_chain(512, spM, dthM, coefM, magM, phiM, idxM);

  // per-thread pack twiddle e^{+i*pi*k/1024}
  float stk, ctk;
  sincosf(PI_F * (float)k * (1.0f / 1024.0f), &stk, &ctk);

  float2 carry = make_float2(0.0f, 0.0f);        // OLA carry, samples 2tid,2tid+1
  const long outbase = (long)b * (NF * HOP);
  const int krA = P2((int)(__brev((uint32_t)k) >> 22));
  const int krB = (k > 0) ? P2((int)(__brev((uint32_t)(MHALF - k)) >> 22)) : P2(1);

  __syncthreads();

  for (int t = tstart; t < tend; ++t) {
    // ---- spectrum (registers) + pack + bit-reversed scatter ----
    { float nz = tf_noise(idxA); idxA += NC; phiA += spA + dthA * nz; magA *= coefA; }
    { float nz = tf_noise(idxB); idxB += NC; phiB += spB + dthB * nz; magB *= coefB; }
    float snA, csA; __sincosf(phiA, &snA, &csA);
    float snB, csB; __sincosf(phiB, &snB, &csB);
    const float x0r = magA * csA, x0i = (k == 0) ? 0.0f : magA * snA;  // c==0 imag zero
    const float x1r = magB * csB, x1i = (k == 0) ? 0.0f : magB * snB;  // c==1024 imag zero
    const float ar = 0.5f * (x0r + x1r);
    const float ai = 0.5f * (x0i - x1i);
    const float dr = x0r - x1r;
    const float di = x0i + x1i;
    const float br = -0.5f * (dr * stk + di * ctk);
    const float bi =  0.5f * (dr * ctk - di * stk);
    z[krA] = make_float2(ar + br, ai + bi);
    if (k > 0) {
      z[krB] = make_float2(ar - br, bi - ai);    // Z[1024-k] by symmetry
    } else {
      // thread 0 also emits Z[512] = (X512.r, -X512.i); brev10(512) = 1
      float nz = tf_noise(idxM); idxM += NC; phiM += spM + dthM * nz; magM *= coefM;
      float snM, csM; __sincosf(phiM, &snM, &csM);
      z[krB] = make_float2(magM * csM, -magM * snM);
    }
    __syncthreads();

    // ---- 1024-pt radix-2 DIT inverse FFT (e^{+i}), packed twiddles ----
    for (int s = 1; s <= 10; ++s) {
      const int half = 1 << (s - 1);
      const int q  = tid >> (s - 1);
      const int rr = tid & (half - 1);
      const int i0 = (q << s) | rr;
      const int i1 = i0 + half;
      const float2 w = tw[half + rr];           // consecutive/broadcast: conflict-free
      const float2 u = z[P2(i0)];
      const float2 v = z[P2(i1)];
      const float tr  = v.x * w.x - v.y * w.y;
      const float ti2 = v.x * w.y + v.y * w.x;
      z[P2(i0)] = make_float2(u.x + tr, u.y + ti2);
      z[P2(i1)] = make_float2(u.x - tr, u.y - ti2);
      __syncthreads();
    }

    // ---- overlap-add: thread owns samples (2tid, 2tid+1) = z[tid];
    //      second-half samples (1024+2tid, 1024+2tid+1) = z[512+tid] -> carry
    {
      const float2 e0 = z[P2(tid)];
      const float2 e1 = z[P2(512 + tid)];
      if (t >= t0) {
        float2* ob = (float2*)(out + outbase + (long)t * HOP) + tid;
        *ob = make_float2(e0.x + carry.x, e0.y + carry.y);
      }
      carry = e1;
    }
    __syncthreads();   // OLA reads must complete before next frame's scatter
  }
}

extern "C" void kernel_launch(void* const* d_in, const int* in_sizes, int n_in,
                              void* d_out, int out_size, void* d_ws, size_t ws_size,
                              hipStream_t stream) {
  (void)in_sizes; (void)n_in; (void)ws_size; (void)out_size;
  const float* amp   = (const float*)d_in[0];
  const float* phase = (const float*)d_in[1];
  const float* decay = (const float*)d_in[2];
  const float* pdith = (const float*)d_in[3];
  float* out = (float*)d_out;
  float* pre = (float*)d_ws;     // 256*1025*3 floats = 3.15 MB

  hipLaunchKernelGGL(prefix_kernel, dim3(NC), dim3(256), 0, stream, pre);

  dim3 grid(B_TOT, NCHUNK);
  dim3 block(NTHREADS);
  hipLaunchKernelGGL(resblock_kernel, grid, block, 0, stream,
                     amp, phase, decay, pdith, pre, out);
}